// Round 3
// baseline (462.627 us; speedup 1.0000x reference)
//
#include <hip/hip_runtime.h>
#include <hip/hip_fp16.h>

typedef _Float16 f16x8 __attribute__((ext_vector_type(8)));
typedef float    f32x4 __attribute__((ext_vector_type(4)));

#define MFMA16(a,b,c) __builtin_amdgcn_mfma_f32_16x16x32_f16(a,b,c,0,0,0)

__device__ __forceinline__ void gload_lds16(const void* g, void* l) {
  __builtin_amdgcn_global_load_lds(
      (const __attribute__((address_space(1))) void*)g,
      (__attribute__((address_space(3))) void*)l, 16, 0, 0);
}

// ---------------- fp32 -> fp16 conversion ----------------
__global__ void cvt_f32_f16(const float* __restrict__ src,
                            _Float16* __restrict__ dst, int n8) {
  int i = blockIdx.x * blockDim.x + threadIdx.x;
  int stride = gridDim.x * blockDim.x;
  for (; i < n8; i += stride) {
    const float4* s = (const float4*)src + 2 * (size_t)i;
    float4 a = s[0], b = s[1];
    f16x8 o;
    o[0]=(_Float16)a.x; o[1]=(_Float16)a.y; o[2]=(_Float16)a.z; o[3]=(_Float16)a.w;
    o[4]=(_Float16)b.x; o[5]=(_Float16)b.y; o[6]=(_Float16)b.z; o[7]=(_Float16)b.w;
    ((f16x8*)dst)[i] = o;
  }
}

// ---------------- cache_V f32 [32][4096][128] -> V^T f16 [32][128][4096] ----------------
__global__ __launch_bounds__(256) void cvt_transpose_v(const float* __restrict__ src,
                                                       _Float16* __restrict__ dst) {
  __shared__ _Float16 t[64][72];   // [d][l], padded
  const int b = blockIdx.x;        // 32 h x 64 l-tiles x 2 d-tiles
  const int h = b >> 7, rest = b & 127;
  const int lt = rest >> 1, dt = rest & 1;
  const int l0 = lt * 64, d0 = dt * 64;
  const int tid = threadIdx.x;
  const int r = tid >> 4, c4 = (tid & 15) * 4;
#pragma unroll
  for (int i = 0; i < 4; i++) {
    int l = r + i * 16;
    float4 v = *(const float4*)&src[((size_t)h * 4096 + l0 + l) * 128 + d0 + c4];
    t[c4 + 0][l] = (_Float16)v.x;
    t[c4 + 1][l] = (_Float16)v.y;
    t[c4 + 2][l] = (_Float16)v.z;
    t[c4 + 3][l] = (_Float16)v.w;
  }
  __syncthreads();
  const int d = tid >> 2, lc = (tid & 3) * 16;
#pragma unroll
  for (int i = 0; i < 2; i++) {
    f16x8 o = *(const f16x8*)&t[d][lc + i * 8];
    *(f16x8*)&dst[((size_t)h * 128 + d0 + d) * 4096 + l0 + lc + i * 8] = o;
  }
}

// ---------------- fused QKV projection GEMM ----------------
// C[512,12288] = X16[512,4096] @ W16[12288,4096]^T  (NT)
// XCD swizzle: blocks sharing a W band land on one XCD's L2.
__global__ __launch_bounds__(256) void qkv_gemm(
    const _Float16* __restrict__ X,
    const _Float16* __restrict__ W,
    _Float16* __restrict__ Q16,
    _Float16* __restrict__ Kc,
    _Float16* __restrict__ Vt16,
    const int* __restrict__ Pp)
{
  __shared__ __align__(16) _Float16 As[128][32];
  __shared__ __align__(16) _Float16 Bs[128][32];
  const int bid = blockIdx.x;            // 384 = 8 xcd * 48
  const int xcd = bid & 7, slot = bid >> 3;  // slot 0..47
  const int nt = xcd * 12 + (slot >> 2);
  const int mt = slot & 3;
  const int m0 = mt * 128, n0 = nt * 128;
  const int tid = threadIdx.x, wave = tid >> 6, lane = tid & 63;
  const int g = lane >> 4, c = lane & 15;
  const int wr = wave >> 1, wc = wave & 1;
  f32x4 acc[4][4] = {};
  const _Float16* ga = X + (size_t)(m0 + wave * 32 + (lane >> 2)) * 4096 + (lane & 3) * 8;
  const _Float16* gb = W + (size_t)(n0 + wave * 32 + (lane >> 2)) * 4096 + (lane & 3) * 8;
  _Float16* la = &As[wave * 32][0];
  _Float16* lb = &Bs[wave * 32][0];
  for (int k0 = 0; k0 < 4096; k0 += 32) {
    __syncthreads();
    gload_lds16(ga + k0,             la);
    gload_lds16(ga + k0 + 16 * 4096, la + 16 * 32);
    gload_lds16(gb + k0,             lb);
    gload_lds16(gb + k0 + 16 * 4096, lb + 16 * 32);
    __syncthreads();
    f16x8 af[4], bf[4];
#pragma unroll
    for (int mi = 0; mi < 4; mi++) af[mi] = *(const f16x8*)&As[wr * 64 + mi * 16 + c][g * 8];
#pragma unroll
    for (int ni = 0; ni < 4; ni++) bf[ni] = *(const f16x8*)&Bs[wc * 64 + ni * 16 + c][g * 8];
#pragma unroll
    for (int mi = 0; mi < 4; mi++)
#pragma unroll
      for (int ni = 0; ni < 4; ni++)
        acc[mi][ni] = MFMA16(af[mi], bf[ni], acc[mi][ni]);
  }
  const int p = Pp[0];
  const int wsel = n0 >> 12;
  const int h = (n0 >> 7) & 31;
#pragma unroll
  for (int mi = 0; mi < 4; mi++) {
#pragma unroll
    for (int ni = 0; ni < 4; ni++) {
#pragma unroll
      for (int j = 0; j < 4; j++) {
        int m = m0 + wr * 64 + mi * 16 + 4 * g + j;
        int d = wc * 64 + ni * 16 + c;
        _Float16 hv = (_Float16)acc[mi][ni][j];
        if (wsel == 0)      Q16[(size_t)(h * 512 + m) * 128 + d] = hv;
        else if (wsel == 1) Kc[(size_t)(h * 4096 + p + m) * 128 + d] = hv;
        else                Vt16[((size_t)h * 128 + d) * 4096 + p + m] = hv;  // transposed
      }
    }
  }
}

// ---------------- flash attention, split-L partials, BARRIER-FREE ----------------
// grid = 1024: 8-XCD swizzled so the 8 mt-blocks of one (ls,h) share an XCD L2.
// Per block: 4 waves x 16 q-rows, 1024 cache positions, K and V^T read from global (L2).
__global__ __launch_bounds__(256, 4) void attn_part(
    const _Float16* __restrict__ Q16,
    const _Float16* __restrict__ Kc,     // [32][4096][128]
    const _Float16* __restrict__ Vt,     // [32][128][4096]
    float* __restrict__ Opart,           // [4][32][512][128] unnormalized
    float* __restrict__ Mpart,           // [4][32][512]
    float* __restrict__ Lpart)           // [4][32][512]
{
  __shared__ __align__(16) _Float16 Pl[4][16][132];   // wave-private P tiles (132: bank-spread)
  const int bid = blockIdx.x;
  const int xcd = bid & 7, slot = bid >> 3;           // slot 0..127
  const int group = xcd + 8 * (slot >> 3);            // 0..127 == ls*32+h
  const int mt = slot & 7;
  const int ls = group >> 5, h = group & 31;
  const int m0 = mt * 64;
  const int tid = threadIdx.x, wave = tid >> 6, lane = tid & 63;
  const int g = lane >> 4, c = lane & 15;
  const _Float16* Qp = Q16 + (size_t)(h * 512 + m0 + wave * 16 + c) * 128;
  f16x8 qf[4];
#pragma unroll
  for (int kc = 0; kc < 4; kc++) qf[kc] = *(const f16x8*)&Qp[kc * 32 + g * 8];
  const _Float16* Kh = Kc + (size_t)h * 4096 * 128;
  const _Float16* Vth = Vt + (size_t)h * 128 * 4096;
  f32x4 o[8] = {};
  float mrow[4] = {-3e38f, -3e38f, -3e38f, -3e38f};
  float lrow[4] = {0.f, 0.f, 0.f, 0.f};
  const int l_begin = ls * 1024, l_end = l_begin + 1024;

  for (int l0 = l_begin; l0 < l_end; l0 += 128) {
    // ---- scores S[16 q-rows][128 kl] via MFMA, K from global (L2) ----
    f32x4 sc[8] = {};
#pragma unroll
    for (int ni = 0; ni < 8; ni++) {
#pragma unroll
      for (int kc = 0; kc < 4; kc++) {
        f16x8 kf = *(const f16x8*)&Kh[(size_t)(l0 + ni * 16 + c) * 128 + kc * 32 + g * 8];
        sc[ni] = MFMA16(qf[kc], kf, sc[ni]);
      }
    }
    // ---- online softmax (rows 4g+j, reduce over 16-lane c-group) ----
    float scale[4];
#pragma unroll
    for (int j = 0; j < 4; j++) {
      float tm = sc[0][j];
#pragma unroll
      for (int ni = 1; ni < 8; ni++) tm = fmaxf(tm, sc[ni][j]);
      tm = fmaxf(tm, __shfl_xor(tm, 1, 64));
      tm = fmaxf(tm, __shfl_xor(tm, 2, 64));
      tm = fmaxf(tm, __shfl_xor(tm, 4, 64));
      tm = fmaxf(tm, __shfl_xor(tm, 8, 64));
      float mn = fmaxf(mrow[j], tm);
      scale[j] = __expf(mrow[j] - mn);
      mrow[j] = mn;
    }
    float rs[4] = {0.f, 0.f, 0.f, 0.f};
#pragma unroll
    for (int ni = 0; ni < 8; ni++) {
#pragma unroll
      for (int j = 0; j < 4; j++) {
        float pv = __expf(sc[ni][j] - mrow[j]);
        sc[ni][j] = pv;
        rs[j] += pv;
      }
    }
#pragma unroll
    for (int j = 0; j < 4; j++) {
      rs[j] += __shfl_xor(rs[j], 1, 64);
      rs[j] += __shfl_xor(rs[j], 2, 64);
      rs[j] += __shfl_xor(rs[j], 4, 64);
      rs[j] += __shfl_xor(rs[j], 8, 64);
      lrow[j] = lrow[j] * scale[j] + rs[j];
    }
#pragma unroll
    for (int dn = 0; dn < 8; dn++)
#pragma unroll
      for (int j = 0; j < 4; j++) o[dn][j] *= scale[j];
    // ---- P -> wave-private LDS (no barrier: only this wave touches Pl[wave]) ----
#pragma unroll
    for (int ni = 0; ni < 8; ni++)
#pragma unroll
      for (int j = 0; j < 4; j++)
        Pl[wave][4 * g + j][ni * 16 + c] = (_Float16)sc[ni][j];
    f16x8 pa[4];
#pragma unroll
    for (int kc = 0; kc < 4; kc++)
      pa[kc] = *(const f16x8*)&Pl[wave][c][kc * 32 + g * 8];
    // ---- PV: o[qr][d] += P[qr][l] * V^T[d][l], V^T from global (L2) ----
#pragma unroll
    for (int dn = 0; dn < 8; dn++) {
#pragma unroll
      for (int kc = 0; kc < 4; kc++) {
        f16x8 vb = *(const f16x8*)&Vth[(size_t)(dn * 16 + c) * 4096 + l0 + kc * 32 + g * 8];
        o[dn] = MFMA16(pa[kc], vb, o[dn]);
      }
    }
  }
  // ---- epilogue: write unnormalized partials ----
  const size_t pbase = ((size_t)(ls * 32 + h) * 512);
#pragma unroll
  for (int dn = 0; dn < 8; dn++) {
#pragma unroll
    for (int j = 0; j < 4; j++) {
      int m = m0 + wave * 16 + 4 * g + j;
      Opart[(pbase + m) * 128 + dn * 16 + c] = o[dn][j];
    }
  }
  if (c == 0) {
#pragma unroll
    for (int j = 0; j < 4; j++) {
      int m = m0 + wave * 16 + 4 * g + j;
      Mpart[pbase + m] = mrow[j];
      Lpart[pbase + m] = lrow[j];
    }
  }
}

// ---------------- combine 4 split-L partials ----------------
__global__ __launch_bounds__(256) void attn_combine(
    const float* __restrict__ Opart,
    const float* __restrict__ Mpart,
    const float* __restrict__ Lpart,
    float* __restrict__ out)
{
  int idx = blockIdx.x * 256 + threadIdx.x;   // 32*512*32 float4s
  int row = idx >> 5;
  int d4  = idx & 31;
  int h = row >> 9, m = row & 511;
  float Ms[4];
  float mx = -3e38f;
#pragma unroll
  for (int s = 0; s < 4; s++) {
    Ms[s] = Mpart[(size_t)(s * 32 + h) * 512 + m];
    mx = fmaxf(mx, Ms[s]);
  }
  float lsum = 0.f;
  float4 acc = make_float4(0.f, 0.f, 0.f, 0.f);
#pragma unroll
  for (int s = 0; s < 4; s++) {
    float w = __expf(Ms[s] - mx);
    lsum += w * Lpart[(size_t)(s * 32 + h) * 512 + m];
    float4 ov = ((const float4*)(Opart + ((size_t)(s * 32 + h) * 512 + m) * 128))[d4];
    acc.x += w * ov.x; acc.y += w * ov.y; acc.z += w * ov.z; acc.w += w * ov.w;
  }
  float inv = 1.f / lsum;
  float4 r = make_float4(acc.x * inv, acc.y * inv, acc.z * inv, acc.w * inv);
  *(float4*)&out[(size_t)m * 4096 + h * 128 + d4 * 4] = r;
}

extern "C" void kernel_launch(void* const* d_in, const int* in_sizes, int n_in,
                              void* d_out, int out_size, void* d_ws, size_t ws_size,
                              hipStream_t stream) {
  const float* X  = (const float*)d_in[0];
  const float* Wq = (const float*)d_in[1];
  const float* Wk = (const float*)d_in[2];
  const float* Wv = (const float*)d_in[3];
  const float* cK = (const float*)d_in[4];
  const float* cV = (const float*)d_in[5];
  const int*   Pp = (const int*)d_in[6];
  float* out = (float*)d_out;

  char* ws = (char*)d_ws;
  _Float16* X16  = (_Float16*)(ws);                           // 4 MB
  _Float16* W16  = (_Float16*)(ws + ((size_t)4   << 20));     // 96 MB  [12288][4096]
  _Float16* Q16  = (_Float16*)(ws + ((size_t)100 << 20));     // 4 MB
  _Float16* K16  = (_Float16*)(ws + ((size_t)104 << 20));     // 32 MB  [32][4096][128]
  _Float16* V16t = (_Float16*)(ws + ((size_t)136 << 20));     // 32 MB  [32][128][4096]
  // partials alias the W16 region (W16 dead after qkv_gemm)
  float* Opart = (float*)(ws + ((size_t)4  << 20));           // 32 MB
  float* Mpart = (float*)(ws + ((size_t)36 << 20));
  float* Lpart = (float*)(ws + ((size_t)37 << 20));

  const int NTH = 256;
  auto cvtl = [&](const float* s, _Float16* d, size_t n) {
    int n8 = (int)(n / 8);
    int grid = (n8 + NTH - 1) / NTH;
    if (grid > 2048) grid = 2048;
    cvt_f32_f16<<<dim3(grid), dim3(NTH), 0, stream>>>(s, d, n8);
  };
  cvtl(X,  X16, (size_t)512 * 4096);
  cvtl(Wq, W16,                          (size_t)4096 * 4096);
  cvtl(Wk, W16 + (size_t)4096 * 4096,    (size_t)4096 * 4096);
  cvtl(Wv, W16 + (size_t)2 * 4096 * 4096,(size_t)4096 * 4096);
  cvtl(cK, K16, (size_t)32 * 4096 * 128);
  cvt_transpose_v<<<dim3(4096), dim3(NTH), 0, stream>>>(cV, V16t);

  qkv_gemm<<<dim3(384), dim3(256), 0, stream>>>(X16, W16, Q16, K16, V16t, Pp);
  attn_part<<<dim3(1024), dim3(256), 0, stream>>>(Q16, K16, V16t, Opart, Mpart, Lpart);
  attn_combine<<<dim3(2048), dim3(256), 0, stream>>>(Opart, Mpart, Lpart, out);
}

// Round 4
// 290.970 us; speedup vs baseline: 1.5899x; 1.5899x over previous
//
#include <hip/hip_runtime.h>
#include <hip/hip_fp16.h>

typedef _Float16 f16x8 __attribute__((ext_vector_type(8)));
typedef float    f32x4 __attribute__((ext_vector_type(4)));

#define MFMA16(a,b,c) __builtin_amdgcn_mfma_f32_16x16x32_f16(a,b,c,0,0,0)

__device__ __forceinline__ void gload_lds16(const void* g, void* l) {
  __builtin_amdgcn_global_load_lds(
      (const __attribute__((address_space(1))) void*)g,
      (__attribute__((address_space(3))) void*)l, 16, 0, 0);
}

// ---------------- fp32 -> fp16 conversion ----------------
__global__ void cvt_f32_f16(const float* __restrict__ src,
                            _Float16* __restrict__ dst, int n8) {
  int i = blockIdx.x * blockDim.x + threadIdx.x;
  int stride = gridDim.x * blockDim.x;
  for (; i < n8; i += stride) {
    const float4* s = (const float4*)src + 2 * (size_t)i;
    float4 a = s[0], b = s[1];
    f16x8 o;
    o[0]=(_Float16)a.x; o[1]=(_Float16)a.y; o[2]=(_Float16)a.z; o[3]=(_Float16)a.w;
    o[4]=(_Float16)b.x; o[5]=(_Float16)b.y; o[6]=(_Float16)b.z; o[7]=(_Float16)b.w;
    ((f16x8*)dst)[i] = o;
  }
}

// ---------------- cache_V f32 [32][4096][128] -> V^T f16 [32][128][4096] ----------------
__global__ __launch_bounds__(256) void cvt_transpose_v(const float* __restrict__ src,
                                                       _Float16* __restrict__ dst) {
  __shared__ _Float16 t[64][72];
  const int b = blockIdx.x;        // 32 h x 64 l-tiles x 2 d-tiles
  const int h = b >> 7, rest = b & 127;
  const int lt = rest >> 1, dt = rest & 1;
  const int l0 = lt * 64, d0 = dt * 64;
  const int tid = threadIdx.x;
  const int r = tid >> 4, c4 = (tid & 15) * 4;
#pragma unroll
  for (int i = 0; i < 4; i++) {
    int l = r + i * 16;
    float4 v = *(const float4*)&src[((size_t)h * 4096 + l0 + l) * 128 + d0 + c4];
    t[c4 + 0][l] = (_Float16)v.x;
    t[c4 + 1][l] = (_Float16)v.y;
    t[c4 + 2][l] = (_Float16)v.z;
    t[c4 + 3][l] = (_Float16)v.w;
  }
  __syncthreads();
  const int d = tid >> 2, lc = (tid & 3) * 16;
#pragma unroll
  for (int i = 0; i < 2; i++) {
    f16x8 o = *(const f16x8*)&t[d][lc + i * 8];
    *(f16x8*)&dst[((size_t)h * 128 + d0 + d) * 4096 + l0 + lc + i * 8] = o;
  }
}

// ---------------- fused QKV projection GEMM ----------------
// C[512,12288] = X16 @ W16^T. Tile 128m x 64n, 768 blocks (3/CU).
__global__ __launch_bounds__(256) void qkv_gemm(
    const _Float16* __restrict__ X,
    const _Float16* __restrict__ W,
    _Float16* __restrict__ Q16,
    _Float16* __restrict__ Kc,
    _Float16* __restrict__ Vt16,
    const int* __restrict__ Pp)
{
  __shared__ __align__(16) _Float16 As[128][32];   // 8KB
  __shared__ __align__(16) _Float16 Bs[64][32];    // 4KB
  const int bid = blockIdx.x;                 // 768 = 8 xcd * 96
  const int xcd = bid & 7, s = bid >> 3;      // s 0..95
  const int nt = xcd * 24 + (s >> 2);         // 24 consecutive n-panels per XCD
  const int mt = s & 3;                       // 4 m-blocks of same nt co-located
  const int m0 = mt * 128, n0 = nt * 64;
  const int tid = threadIdx.x, wave = tid >> 6, lane = tid & 63;
  const int g = lane >> 4, c = lane & 15;
  const int wr = wave >> 1, wc = wave & 1;    // wave = 64m x 32n
  f32x4 acc[4][2] = {};
  const int arow0 = (lane >> 2);              // within 16-row chunk
  const int acol  = (lane & 3) * 8;
  for (int k0 = 0; k0 < 4096; k0 += 32) {
    __syncthreads();
#pragma unroll
    for (int p = 0; p < 2; p++) {
      int chunk = p * 4 + wave;               // 0..7, 16 rows each
      int row = chunk * 16 + arow0;
      gload_lds16(X + (size_t)(m0 + row) * 4096 + k0 + acol,
                  (char*)As + chunk * 1024);
    }
    {
      int row = wave * 16 + arow0;
      gload_lds16(W + (size_t)(n0 + row) * 4096 + k0 + acol,
                  (char*)Bs + wave * 1024);
    }
    __syncthreads();
    f16x8 af[4], bf[2];
#pragma unroll
    for (int mi = 0; mi < 4; mi++) af[mi] = *(const f16x8*)&As[wr * 64 + mi * 16 + c][g * 8];
#pragma unroll
    for (int ni = 0; ni < 2; ni++) bf[ni] = *(const f16x8*)&Bs[wc * 32 + ni * 16 + c][g * 8];
#pragma unroll
    for (int mi = 0; mi < 4; mi++)
#pragma unroll
      for (int ni = 0; ni < 2; ni++)
        acc[mi][ni] = MFMA16(af[mi], bf[ni], acc[mi][ni]);
  }
  const int p = Pp[0];
  const int wsel = n0 >> 12;
  const int nq = n0 & 4095;
  const int h = nq >> 7;
  const int dbase = nq & 64;
#pragma unroll
  for (int mi = 0; mi < 4; mi++) {
#pragma unroll
    for (int ni = 0; ni < 2; ni++) {
#pragma unroll
      for (int j = 0; j < 4; j++) {
        int m = m0 + wr * 64 + mi * 16 + 4 * g + j;
        int d = dbase + wc * 32 + ni * 16 + c;
        _Float16 hv = (_Float16)acc[mi][ni][j];
        if (wsel == 0)      Q16[(size_t)(h * 512 + m) * 128 + d] = hv;
        else if (wsel == 1) Kc[(size_t)(h * 4096 + p + m) * 128 + d] = hv;
        else                Vt16[((size_t)h * 128 + d) * 4096 + p + m] = hv;
      }
    }
  }
}

// ---------------- flash attention: LDS-staged K/V, 8 waves x 32 q-rows ----------------
// grid = 256 (1/CU): 4 lsplits x 32 heads x 2 m-tiles(256 rows). BL=64.
// K/V^T staged via global_load_lds with XOR-swizzled GLOBAL source (linear LDS dest),
// fragments read with matching XOR -> conflict-free.
__global__ __launch_bounds__(512, 2) void attn_part(
    const _Float16* __restrict__ Q16,
    const _Float16* __restrict__ Kc,     // [32][4096][128]
    const _Float16* __restrict__ Vt,     // [32][128][4096]
    float* __restrict__ Opart,           // [4][32][512][128]
    float* __restrict__ Mpart,           // [4][32][512]
    float* __restrict__ Lpart)           // [4][32][512]
{
  __shared__ __align__(16) _Float16 Ks[64 * 128];     // 16KB: [64 l][128 d], swizzled
  __shared__ __align__(16) _Float16 Vs[128 * 64];     // 16KB: [128 d][64 l], swizzled
  __shared__ __align__(16) _Float16 Pl[8][32][68];    // 34KB: per-wave P
  const int bid = blockIdx.x;
  const int xcd = bid & 7, s = bid >> 3;              // s 0..31
  const int group = xcd * 16 + (s >> 1);              // ls*32+h ; mt pair same XCD
  const int mt = s & 1;
  const int ls = group >> 5, h = group & 31;
  const int m0 = mt * 256;
  const int tid = threadIdx.x, wave = tid >> 6, lane = tid & 63;
  const int g = lane >> 4, c = lane & 15;
  const int mw = m0 + wave * 32;
  const _Float16* Kh  = Kc + (size_t)h * 4096 * 128;
  const _Float16* Vth = Vt + (size_t)h * 128 * 4096;
  f16x8 qf[2][4];
#pragma unroll
  for (int mi = 0; mi < 2; mi++)
#pragma unroll
    for (int kc = 0; kc < 4; kc++)
      qf[mi][kc] = *(const f16x8*)&Q16[(size_t)(h * 512 + mw + mi * 16 + c) * 128 + kc * 32 + g * 8];
  f32x4 o[2][8] = {};
  float mrow[2][4], lrow[2][4];
#pragma unroll
  for (int mi = 0; mi < 2; mi++)
#pragma unroll
    for (int j = 0; j < 4; j++) { mrow[mi][j] = -3e38f; lrow[mi][j] = 0.f; }
  // staging lane constants
  const int klr = lane >> 4, klb = (lane & 15) * 16;  // K: 4 rows/chunk
  const int vlr = lane >> 3, vlb = (lane & 7) * 16;   // V: 8 rows/chunk

  const int l_begin = ls * 1024;
  for (int l0 = l_begin; l0 < l_begin + 1024; l0 += 64) {
    __syncthreads();   // all waves done reading prev tile
#pragma unroll
    for (int p = 0; p < 2; p++) {
      int chunk = p * 8 + wave;
      int kr = chunk * 4 + klr;                       // 0..63
      gload_lds16((const char*)Kh + (size_t)(l0 + kr) * 256 + (klb ^ ((kr & 7) << 4)),
                  (char*)Ks + chunk * 1024);
      int vd = chunk * 8 + vlr;                       // 0..127
      gload_lds16((const char*)Vth + (size_t)vd * 8192 + (size_t)l0 * 2 + (vlb ^ ((vd & 7) << 4)),
                  (char*)Vs + chunk * 1024);
    }
    __syncthreads();   // staged data visible (vmcnt drained by barrier)
    // ---- QK^T: sc[mi][ni] over 64 cols ----
    f32x4 sc[2][4] = {};
#pragma unroll
    for (int ni = 0; ni < 4; ni++) {
      int kr = ni * 16 + c;
      f16x8 kf[4];
#pragma unroll
      for (int kc = 0; kc < 4; kc++)
        kf[kc] = *(const f16x8*)((const char*)Ks + kr * 256 + ((kc * 64 + g * 16) ^ ((kr & 7) << 4)));
#pragma unroll
      for (int mi = 0; mi < 2; mi++)
#pragma unroll
        for (int kc = 0; kc < 4; kc++)
          sc[mi][ni] = MFMA16(qf[mi][kc], kf[kc], sc[mi][ni]);
    }
    // ---- online softmax ----
#pragma unroll
    for (int mi = 0; mi < 2; mi++) {
      float scale[4];
#pragma unroll
      for (int j = 0; j < 4; j++) {
        float tm = sc[mi][0][j];
#pragma unroll
        for (int ni = 1; ni < 4; ni++) tm = fmaxf(tm, sc[mi][ni][j]);
        tm = fmaxf(tm, __shfl_xor(tm, 1, 64));
        tm = fmaxf(tm, __shfl_xor(tm, 2, 64));
        tm = fmaxf(tm, __shfl_xor(tm, 4, 64));
        tm = fmaxf(tm, __shfl_xor(tm, 8, 64));
        float mn = fmaxf(mrow[mi][j], tm);
        scale[j] = __expf(mrow[mi][j] - mn);
        mrow[mi][j] = mn;
      }
      float rs[4] = {0.f, 0.f, 0.f, 0.f};
#pragma unroll
      for (int ni = 0; ni < 4; ni++) {
#pragma unroll
        for (int j = 0; j < 4; j++) {
          float pv = __expf(sc[mi][ni][j] - mrow[mi][j]);
          sc[mi][ni][j] = pv;
          rs[j] += pv;
        }
      }
#pragma unroll
      for (int j = 0; j < 4; j++) {
        rs[j] += __shfl_xor(rs[j], 1, 64);
        rs[j] += __shfl_xor(rs[j], 2, 64);
        rs[j] += __shfl_xor(rs[j], 4, 64);
        rs[j] += __shfl_xor(rs[j], 8, 64);
        lrow[mi][j] = lrow[mi][j] * scale[j] + rs[j];
      }
#pragma unroll
      for (int dn = 0; dn < 8; dn++)
#pragma unroll
        for (int j = 0; j < 4; j++) o[mi][dn][j] *= scale[j];
      // ---- P -> wave-private LDS ----
#pragma unroll
      for (int ni = 0; ni < 4; ni++)
#pragma unroll
        for (int j = 0; j < 4; j++)
          Pl[wave][mi * 16 + 4 * g + j][ni * 16 + c] = (_Float16)sc[mi][ni][j];
    }
    f16x8 pa[2][2];
#pragma unroll
    for (int mi = 0; mi < 2; mi++)
#pragma unroll
      for (int kc = 0; kc < 2; kc++)
        pa[mi][kc] = *(const f16x8*)&Pl[wave][mi * 16 + c][kc * 32 + g * 8];
    // ---- PV ----
#pragma unroll
    for (int dn = 0; dn < 8; dn++) {
      int vr = dn * 16 + c;
#pragma unroll
      for (int kc = 0; kc < 2; kc++) {
        f16x8 vb = *(const f16x8*)((const char*)Vs + vr * 128 + ((kc * 64 + g * 16) ^ ((vr & 7) << 4)));
#pragma unroll
        for (int mi = 0; mi < 2; mi++)
          o[mi][dn] = MFMA16(pa[mi][kc], vb, o[mi][dn]);
      }
    }
  }
  // ---- epilogue ----
  const size_t pbase = ((size_t)(ls * 32 + h) * 512);
#pragma unroll
  for (int mi = 0; mi < 2; mi++) {
#pragma unroll
    for (int dn = 0; dn < 8; dn++) {
#pragma unroll
      for (int j = 0; j < 4; j++) {
        int m = mw + mi * 16 + 4 * g + j;
        Opart[(pbase + m) * 128 + dn * 16 + c] = o[mi][dn][j];
      }
    }
  }
  if (c == 0) {
#pragma unroll
    for (int mi = 0; mi < 2; mi++)
#pragma unroll
      for (int j = 0; j < 4; j++) {
        int m = mw + mi * 16 + 4 * g + j;
        Mpart[pbase + m] = mrow[mi][j];
        Lpart[pbase + m] = lrow[mi][j];
      }
  }
}

// ---------------- combine 4 split-L partials ----------------
__global__ __launch_bounds__(256) void attn_combine(
    const float* __restrict__ Opart,
    const float* __restrict__ Mpart,
    const float* __restrict__ Lpart,
    float* __restrict__ out)
{
  int idx = blockIdx.x * 256 + threadIdx.x;
  int row = idx >> 5;
  int d4  = idx & 31;
  int h = row >> 9, m = row & 511;
  float Ms[4];
  float mx = -3e38f;
#pragma unroll
  for (int s = 0; s < 4; s++) {
    Ms[s] = Mpart[(size_t)(s * 32 + h) * 512 + m];
    mx = fmaxf(mx, Ms[s]);
  }
  float lsum = 0.f;
  float4 acc = make_float4(0.f, 0.f, 0.f, 0.f);
#pragma unroll
  for (int s = 0; s < 4; s++) {
    float w = __expf(Ms[s] - mx);
    lsum += w * Lpart[(size_t)(s * 32 + h) * 512 + m];
    float4 ov = ((const float4*)(Opart + ((size_t)(s * 32 + h) * 512 + m) * 128))[d4];
    acc.x += w * ov.x; acc.y += w * ov.y; acc.z += w * ov.z; acc.w += w * ov.w;
  }
  float inv = 1.f / lsum;
  float4 r = make_float4(acc.x * inv, acc.y * inv, acc.z * inv, acc.w * inv);
  *(float4*)&out[(size_t)m * 4096 + h * 128 + d4 * 4] = r;
}

extern "C" void kernel_launch(void* const* d_in, const int* in_sizes, int n_in,
                              void* d_out, int out_size, void* d_ws, size_t ws_size,
                              hipStream_t stream) {
  const float* X  = (const float*)d_in[0];
  const float* Wq = (const float*)d_in[1];
  const float* Wk = (const float*)d_in[2];
  const float* Wv = (const float*)d_in[3];
  const float* cK = (const float*)d_in[4];
  const float* cV = (const float*)d_in[5];
  const int*   Pp = (const int*)d_in[6];
  float* out = (float*)d_out;

  char* ws = (char*)d_ws;
  _Float16* X16  = (_Float16*)(ws);                           // 4 MB
  _Float16* W16  = (_Float16*)(ws + ((size_t)4   << 20));     // 96 MB
  _Float16* Q16  = (_Float16*)(ws + ((size_t)100 << 20));     // 4 MB
  _Float16* K16  = (_Float16*)(ws + ((size_t)104 << 20));     // 32 MB [32][4096][128]
  _Float16* V16t = (_Float16*)(ws + ((size_t)136 << 20));     // 32 MB [32][128][4096]
  float* Opart = (float*)(ws + ((size_t)4  << 20));           // 32 MB (aliases dead W16)
  float* Mpart = (float*)(ws + ((size_t)36 << 20));
  float* Lpart = (float*)(ws + ((size_t)37 << 20));

  const int NTH = 256;
  auto cvtl = [&](const float* s, _Float16* d, size_t n) {
    int n8 = (int)(n / 8);
    int grid = (n8 + NTH - 1) / NTH;
    if (grid > 2048) grid = 2048;
    cvt_f32_f16<<<dim3(grid), dim3(NTH), 0, stream>>>(s, d, n8);
  };
  cvtl(X,  X16, (size_t)512 * 4096);
  cvtl(Wq, W16,                          (size_t)4096 * 4096);
  cvtl(Wk, W16 + (size_t)4096 * 4096,    (size_t)4096 * 4096);
  cvtl(Wv, W16 + (size_t)2 * 4096 * 4096,(size_t)4096 * 4096);
  cvtl(cK, K16, (size_t)32 * 4096 * 128);
  cvt_transpose_v<<<dim3(4096), dim3(NTH), 0, stream>>>(cV, V16t);

  qkv_gemm<<<dim3(768), dim3(256), 0, stream>>>(X16, W16, Q16, K16, V16t, Pp);
  attn_part<<<dim3(256), dim3(512), 0, stream>>>(Q16, K16, V16t, Opart, Mpart, Lpart);
  attn_combine<<<dim3(2048), dim3(256), 0, stream>>>(Opart, Mpart, Lpart, out);
}

// Round 5
// 233.034 us; speedup vs baseline: 1.9852x; 1.2486x over previous
//
#include <hip/hip_runtime.h>
#include <hip/hip_fp16.h>

typedef _Float16 f16x8 __attribute__((ext_vector_type(8)));
typedef float    f32x4 __attribute__((ext_vector_type(4)));

#define MFMA16(a,b,c) __builtin_amdgcn_mfma_f32_16x16x32_f16(a,b,c,0,0,0)

__device__ __forceinline__ void gload_lds16(const void* g, void* l) {
  __builtin_amdgcn_global_load_lds(
      (const __attribute__((address_space(1))) void*)g,
      (__attribute__((address_space(3))) void*)l, 16, 0, 0);
}

// ---------------- fp32 -> fp16 conversion ----------------
__global__ void cvt_f32_f16(const float* __restrict__ src,
                            _Float16* __restrict__ dst, int n8) {
  int i = blockIdx.x * blockDim.x + threadIdx.x;
  int stride = gridDim.x * blockDim.x;
  for (; i < n8; i += stride) {
    const float4* s = (const float4*)src + 2 * (size_t)i;
    float4 a = s[0], b = s[1];
    f16x8 o;
    o[0]=(_Float16)a.x; o[1]=(_Float16)a.y; o[2]=(_Float16)a.z; o[3]=(_Float16)a.w;
    o[4]=(_Float16)b.x; o[5]=(_Float16)b.y; o[6]=(_Float16)b.z; o[7]=(_Float16)b.w;
    ((f16x8*)dst)[i] = o;
  }
}

// ---------------- cache_V f32 [32][4096][128] -> V^T f16 [32][128][4096] ----------------
__global__ __launch_bounds__(256) void cvt_transpose_v(const float* __restrict__ src,
                                                       _Float16* __restrict__ dst) {
  __shared__ _Float16 t[64][72];
  const int b = blockIdx.x;        // 32 h x 64 l-tiles x 2 d-tiles
  const int h = b >> 7, rest = b & 127;
  const int lt = rest >> 1, dt = rest & 1;
  const int l0 = lt * 64, d0 = dt * 64;
  const int tid = threadIdx.x;
  const int r = tid >> 4, c4 = (tid & 15) * 4;
#pragma unroll
  for (int i = 0; i < 4; i++) {
    int l = r + i * 16;
    float4 v = *(const float4*)&src[((size_t)h * 4096 + l0 + l) * 128 + d0 + c4];
    t[c4 + 0][l] = (_Float16)v.x;
    t[c4 + 1][l] = (_Float16)v.y;
    t[c4 + 2][l] = (_Float16)v.z;
    t[c4 + 3][l] = (_Float16)v.w;
  }
  __syncthreads();
  const int d = tid >> 2, lc = (tid & 3) * 16;
#pragma unroll
  for (int i = 0; i < 2; i++) {
    f16x8 o = *(const f16x8*)&t[d][lc + i * 8];
    *(f16x8*)&dst[((size_t)h * 128 + d0 + d) * 4096 + l0 + lc + i * 8] = o;
  }
}

// ---------------- fused QKV GEMM, W read f32 directly (fused cvt) ----------------
// C[512,12288] = X16 @ [Wq;Wk;Wv]^T. Tile 128m x 64n, BK=64, 768 blocks (3/CU).
// A: global_load_lds from f16 X, pre-swizzled source. B: f32 reg-stage + cvt +
// swizzled ds_write, prefetched one K-step ahead (drains at the same barrier).
__global__ __launch_bounds__(256) void qkv_gemm(
    const _Float16* __restrict__ X,
    const float* __restrict__ Wq,
    const float* __restrict__ Wk,
    const float* __restrict__ Wv,
    _Float16* __restrict__ Q16,
    _Float16* __restrict__ Kc,
    _Float16* __restrict__ Vt16,
    const int* __restrict__ Pp)
{
  __shared__ __align__(16) _Float16 As[128 * 64];   // 16KB, 128B rows, XOR-swizzled
  __shared__ __align__(16) _Float16 Bs[64 * 64];    // 8KB,  128B rows, XOR-swizzled
  const int bid = blockIdx.x;                 // 768 = 8 xcd * 96
  const int xcd = bid & 7, s = bid >> 3;      // s 0..95
  const int nt = xcd * 24 + (s >> 2);         // 0..191: 24 consecutive n-panels/XCD
  const int mt = s & 3;                       // 4 m-blocks of same panel co-XCD
  const int m0 = mt * 128, n0 = nt * 64;
  const int tid = threadIdx.x, wave = tid >> 6, lane = tid & 63;
  const int g = lane >> 4, c = lane & 15;
  const int wr = wave >> 1, wc = wave & 1;    // wave = 64m x 32n
  // W source select (tile never crosses a 4096 boundary)
  const float* Wp = (n0 < 4096) ? Wq : ((n0 < 8192) ? Wk : Wv);
  const int n0l = n0 & 4095;
  // A staging: chunk = wave*4+p, 8 rows/chunk; lane -> row ar, col byte acs
  const int ar  = lane >> 3;
  const int acs = (lane & 7) * 16;
  // B staging: row = tid>>2, 16 consecutive f32 at col (tid&3)*16
  const int brow = tid >> 2;
  const int bc32 = (tid & 3) * 16;
  const float* wsrc = Wp + (size_t)(n0l + brow) * 4096 + bc32;
  const int bsw = (brow & 7) << 4;
  float4 breg[4];
#pragma unroll
  for (int i = 0; i < 4; i++) breg[i] = *(const float4*)(wsrc + i * 4);

  f32x4 acc[4][2] = {};
  for (int k0 = 0; k0 < 4096; k0 += 64) {
    __syncthreads();
    // ---- A -> LDS (async, swizzled global source, linear dest) ----
#pragma unroll
    for (int p = 0; p < 4; p++) {
      int chunk = wave * 4 + p;
      int row = chunk * 8 + ar;
      gload_lds16((const char*)(X + (size_t)(m0 + row) * 4096 + k0) + (acs ^ ((row & 7) << 4)),
                  (char*)As + chunk * 1024);
    }
    // ---- B: cvt prefetched regs -> swizzled LDS; prefetch next K-step ----
    {
      const float* bv = (const float*)breg;
      f16x8 h0, h1;
#pragma unroll
      for (int i = 0; i < 8; i++) { h0[i] = (_Float16)bv[i]; h1[i] = (_Float16)bv[8 + i]; }
      char* rb = (char*)Bs + brow * 128;
      *(f16x8*)(rb + (((tid & 3) * 32)      ^ bsw)) = h0;
      *(f16x8*)(rb + (((tid & 3) * 32 + 16) ^ bsw)) = h1;
      if (k0 + 64 < 4096) {
        const float* ns = wsrc + k0 + 64;
#pragma unroll
        for (int i = 0; i < 4; i++) breg[i] = *(const float4*)(ns + i * 4);
      }
    }
    __syncthreads();   // drains A gload_lds (+ B prefetch) in one wait
    // ---- fragments (matching XOR) + MFMA ----
    f16x8 af[2][4], bf[2][2];
#pragma unroll
    for (int mi = 0; mi < 4; mi++) {
      int row = wr * 64 + mi * 16 + c;
      int sw = (row & 7) << 4;
#pragma unroll
      for (int kc = 0; kc < 2; kc++)
        af[kc][mi] = *(const f16x8*)((const char*)As + row * 128 + ((kc * 64 + g * 16) ^ sw));
    }
#pragma unroll
    for (int ni = 0; ni < 2; ni++) {
      int row = wc * 32 + ni * 16 + c;
      int sw = (row & 7) << 4;
#pragma unroll
      for (int kc = 0; kc < 2; kc++)
        bf[kc][ni] = *(const f16x8*)((const char*)Bs + row * 128 + ((kc * 64 + g * 16) ^ sw));
    }
#pragma unroll
    for (int kc = 0; kc < 2; kc++)
#pragma unroll
      for (int mi = 0; mi < 4; mi++)
#pragma unroll
        for (int ni = 0; ni < 2; ni++)
          acc[mi][ni] = MFMA16(af[kc][mi], bf[kc][ni], acc[mi][ni]);
  }
  // ---- epilogue: cvt f16 + scatter ----
  const int p = Pp[0];
  const int wsel = n0 >> 12;
  const int h = (n0 & 4095) >> 7;
  const int dbase = n0 & 127;                 // 0 or 64
#pragma unroll
  for (int mi = 0; mi < 4; mi++) {
#pragma unroll
    for (int ni = 0; ni < 2; ni++) {
#pragma unroll
      for (int j = 0; j < 4; j++) {
        int m = m0 + wr * 64 + mi * 16 + 4 * g + j;
        int d = dbase + wc * 32 + ni * 16 + c;
        _Float16 hv = (_Float16)acc[mi][ni][j];
        if (wsel == 0)      Q16[(size_t)(h * 512 + m) * 128 + d] = hv;
        else if (wsel == 1) Kc[(size_t)(h * 4096 + p + m) * 128 + d] = hv;
        else                Vt16[((size_t)h * 128 + d) * 4096 + p + m] = hv;
      }
    }
  }
}

// ---------------- flash attention: LDS-staged K/V, 8 waves x 32 q-rows ----------------
// grid = 256 (1/CU): 4 lsplits x 32 heads x 2 m-tiles(256 rows). BL=64.
__global__ __launch_bounds__(512, 2) void attn_part(
    const _Float16* __restrict__ Q16,
    const _Float16* __restrict__ Kc,     // [32][4096][128]
    const _Float16* __restrict__ Vt,     // [32][128][4096]
    float* __restrict__ Opart,           // [4][32][512][128]
    float* __restrict__ Mpart,           // [4][32][512]
    float* __restrict__ Lpart)           // [4][32][512]
{
  __shared__ __align__(16) _Float16 Ks[64 * 128];
  __shared__ __align__(16) _Float16 Vs[128 * 64];
  __shared__ __align__(16) _Float16 Pl[8][32][68];
  const int bid = blockIdx.x;
  const int xcd = bid & 7, s = bid >> 3;
  const int group = xcd * 16 + (s >> 1);
  const int mt = s & 1;
  const int ls = group >> 5, h = group & 31;
  const int m0 = mt * 256;
  const int tid = threadIdx.x, wave = tid >> 6, lane = tid & 63;
  const int g = lane >> 4, c = lane & 15;
  const int mw = m0 + wave * 32;
  const _Float16* Kh  = Kc + (size_t)h * 4096 * 128;
  const _Float16* Vth = Vt + (size_t)h * 128 * 4096;
  f16x8 qf[2][4];
#pragma unroll
  for (int mi = 0; mi < 2; mi++)
#pragma unroll
    for (int kc = 0; kc < 4; kc++)
      qf[mi][kc] = *(const f16x8*)&Q16[(size_t)(h * 512 + mw + mi * 16 + c) * 128 + kc * 32 + g * 8];
  f32x4 o[2][8] = {};
  float mrow[2][4], lrow[2][4];
#pragma unroll
  for (int mi = 0; mi < 2; mi++)
#pragma unroll
    for (int j = 0; j < 4; j++) { mrow[mi][j] = -3e38f; lrow[mi][j] = 0.f; }
  const int klr = lane >> 4, klb = (lane & 15) * 16;
  const int vlr = lane >> 3, vlb = (lane & 7) * 16;

  const int l_begin = ls * 1024;
  for (int l0 = l_begin; l0 < l_begin + 1024; l0 += 64) {
    __syncthreads();
#pragma unroll
    for (int p = 0; p < 2; p++) {
      int chunk = p * 8 + wave;
      int kr = chunk * 4 + klr;
      gload_lds16((const char*)Kh + (size_t)(l0 + kr) * 256 + (klb ^ ((kr & 7) << 4)),
                  (char*)Ks + chunk * 1024);
      int vd = chunk * 8 + vlr;
      gload_lds16((const char*)Vth + (size_t)vd * 8192 + (size_t)l0 * 2 + (vlb ^ ((vd & 7) << 4)),
                  (char*)Vs + chunk * 1024);
    }
    __syncthreads();
    f32x4 sc[2][4] = {};
#pragma unroll
    for (int ni = 0; ni < 4; ni++) {
      int kr = ni * 16 + c;
      f16x8 kf[4];
#pragma unroll
      for (int kc = 0; kc < 4; kc++)
        kf[kc] = *(const f16x8*)((const char*)Ks + kr * 256 + ((kc * 64 + g * 16) ^ ((kr & 7) << 4)));
#pragma unroll
      for (int mi = 0; mi < 2; mi++)
#pragma unroll
        for (int kc = 0; kc < 4; kc++)
          sc[mi][ni] = MFMA16(qf[mi][kc], kf[kc], sc[mi][ni]);
    }
#pragma unroll
    for (int mi = 0; mi < 2; mi++) {
      float scale[4];
#pragma unroll
      for (int j = 0; j < 4; j++) {
        float tm = sc[mi][0][j];
#pragma unroll
        for (int ni = 1; ni < 4; ni++) tm = fmaxf(tm, sc[mi][ni][j]);
        tm = fmaxf(tm, __shfl_xor(tm, 1, 64));
        tm = fmaxf(tm, __shfl_xor(tm, 2, 64));
        tm = fmaxf(tm, __shfl_xor(tm, 4, 64));
        tm = fmaxf(tm, __shfl_xor(tm, 8, 64));
        float mn = fmaxf(mrow[mi][j], tm);
        scale[j] = __expf(mrow[mi][j] - mn);
        mrow[mi][j] = mn;
      }
      float rs[4] = {0.f, 0.f, 0.f, 0.f};
#pragma unroll
      for (int ni = 0; ni < 4; ni++) {
#pragma unroll
        for (int j = 0; j < 4; j++) {
          float pv = __expf(sc[mi][ni][j] - mrow[mi][j]);
          sc[mi][ni][j] = pv;
          rs[j] += pv;
        }
      }
#pragma unroll
      for (int j = 0; j < 4; j++) {
        rs[j] += __shfl_xor(rs[j], 1, 64);
        rs[j] += __shfl_xor(rs[j], 2, 64);
        rs[j] += __shfl_xor(rs[j], 4, 64);
        rs[j] += __shfl_xor(rs[j], 8, 64);
        lrow[mi][j] = lrow[mi][j] * scale[j] + rs[j];
      }
#pragma unroll
      for (int dn = 0; dn < 8; dn++)
#pragma unroll
        for (int j = 0; j < 4; j++) o[mi][dn][j] *= scale[j];
#pragma unroll
      for (int ni = 0; ni < 4; ni++)
#pragma unroll
        for (int j = 0; j < 4; j++)
          Pl[wave][mi * 16 + 4 * g + j][ni * 16 + c] = (_Float16)sc[mi][ni][j];
    }
    f16x8 pa[2][2];
#pragma unroll
    for (int mi = 0; mi < 2; mi++)
#pragma unroll
      for (int kc = 0; kc < 2; kc++)
        pa[mi][kc] = *(const f16x8*)&Pl[wave][mi * 16 + c][kc * 32 + g * 8];
#pragma unroll
    for (int dn = 0; dn < 8; dn++) {
      int vr = dn * 16 + c;
#pragma unroll
      for (int kc = 0; kc < 2; kc++) {
        f16x8 vb = *(const f16x8*)((const char*)Vs + vr * 128 + ((kc * 64 + g * 16) ^ ((vr & 7) << 4)));
#pragma unroll
        for (int mi = 0; mi < 2; mi++)
          o[mi][dn] = MFMA16(pa[mi][kc], vb, o[mi][dn]);
      }
    }
  }
  const size_t pbase = ((size_t)(ls * 32 + h) * 512);
#pragma unroll
  for (int mi = 0; mi < 2; mi++) {
#pragma unroll
    for (int dn = 0; dn < 8; dn++) {
#pragma unroll
      for (int j = 0; j < 4; j++) {
        int m = mw + mi * 16 + 4 * g + j;
        Opart[(pbase + m) * 128 + dn * 16 + c] = o[mi][dn][j];
      }
    }
  }
  if (c == 0) {
#pragma unroll
    for (int mi = 0; mi < 2; mi++)
#pragma unroll
      for (int j = 0; j < 4; j++) {
        int m = mw + mi * 16 + 4 * g + j;
        Mpart[pbase + m] = mrow[mi][j];
        Lpart[pbase + m] = lrow[mi][j];
      }
  }
}

// ---------------- combine 4 split-L partials ----------------
__global__ __launch_bounds__(256) void attn_combine(
    const float* __restrict__ Opart,
    const float* __restrict__ Mpart,
    const float* __restrict__ Lpart,
    float* __restrict__ out)
{
  int idx = blockIdx.x * 256 + threadIdx.x;
  int row = idx >> 5;
  int d4  = idx & 31;
  int h = row >> 9, m = row & 511;
  float Ms[4];
  float mx = -3e38f;
#pragma unroll
  for (int s = 0; s < 4; s++) {
    Ms[s] = Mpart[(size_t)(s * 32 + h) * 512 + m];
    mx = fmaxf(mx, Ms[s]);
  }
  float lsum = 0.f;
  float4 acc = make_float4(0.f, 0.f, 0.f, 0.f);
#pragma unroll
  for (int s = 0; s < 4; s++) {
    float w = __expf(Ms[s] - mx);
    lsum += w * Lpart[(size_t)(s * 32 + h) * 512 + m];
    float4 ov = ((const float4*)(Opart + ((size_t)(s * 32 + h) * 512 + m) * 128))[d4];
    acc.x += w * ov.x; acc.y += w * ov.y; acc.z += w * ov.z; acc.w += w * ov.w;
  }
  float inv = 1.f / lsum;
  float4 r = make_float4(acc.x * inv, acc.y * inv, acc.z * inv, acc.w * inv);
  *(float4*)&out[(size_t)m * 4096 + h * 128 + d4 * 4] = r;
}

extern "C" void kernel_launch(void* const* d_in, const int* in_sizes, int n_in,
                              void* d_out, int out_size, void* d_ws, size_t ws_size,
                              hipStream_t stream) {
  const float* X  = (const float*)d_in[0];
  const float* Wq = (const float*)d_in[1];
  const float* Wk = (const float*)d_in[2];
  const float* Wv = (const float*)d_in[3];
  const float* cK = (const float*)d_in[4];
  const float* cV = (const float*)d_in[5];
  const int*   Pp = (const int*)d_in[6];
  float* out = (float*)d_out;

  char* ws = (char*)d_ws;
  _Float16* X16  = (_Float16*)(ws);                           // 4 MB
  _Float16* Q16  = (_Float16*)(ws + ((size_t)100 << 20));     // 4 MB
  _Float16* K16  = (_Float16*)(ws + ((size_t)104 << 20));     // 32 MB [32][4096][128]
  _Float16* V16t = (_Float16*)(ws + ((size_t)136 << 20));     // 32 MB [32][128][4096]
  float* Opart = (float*)(ws + ((size_t)4  << 20));           // 32 MB
  float* Mpart = (float*)(ws + ((size_t)36 << 20));
  float* Lpart = (float*)(ws + ((size_t)37 << 20));

  const int NTH = 256;
  auto cvtl = [&](const float* s, _Float16* d, size_t n) {
    int n8 = (int)(n / 8);
    int grid = (n8 + NTH - 1) / NTH;
    if (grid > 2048) grid = 2048;
    cvt_f32_f16<<<dim3(grid), dim3(NTH), 0, stream>>>(s, d, n8);
  };
  cvtl(X,  X16, (size_t)512 * 4096);
  cvtl(cK, K16, (size_t)32 * 4096 * 128);
  cvt_transpose_v<<<dim3(4096), dim3(NTH), 0, stream>>>(cV, V16t);

  qkv_gemm<<<dim3(768), dim3(256), 0, stream>>>(X16, Wq, Wk, Wv, Q16, K16, V16t, Pp);
  attn_part<<<dim3(256), dim3(512), 0, stream>>>(Q16, K16, V16t, Opart, Mpart, Lpart);
  attn_combine<<<dim3(2048), dim3(256), 0, stream>>>(Opart, Mpart, Lpart, out);
}